// Round 6
// baseline (3739.429 us; speedup 1.0000x reference)
//
#include <hip/hip_runtime.h>
#include <cstdint>
#include <cstddef>

#define B_SZ 32
#define NPTS 16384
#define NSAMP 2048
#define F_IN 64
#define C_IN 67
#define D_OUT 128
#define FPS_THREADS 512
#define PPT 32                  // points per thread
#define NWAVE (FPS_THREADS / 64)

// one DPP max step: v = max(v, lanes-moved(v)); invalid lanes keep old (=v)
template <int CTRL>
__device__ __forceinline__ float dpp_max(float v) {
    const int iv = __float_as_int(v);
    const int mv = __builtin_amdgcn_update_dpp(iv, iv, CTRL, 0xf, 0xf, false);
    return fmaxf(v, __int_as_float(mv));
}

// ---------------------------------------------------------------------------
// FPS: one block per batch, 512 threads, 32 pts/thread. px,py,dist in regs
// (96 floats), pz in LDS (64 KB) to keep state inside arch VGPRs.
// Per iteration:
//   A. dist update (explicit rn ops, bit-matches ref) + value-only max
//   B. wave max via DPP chain (row_shr 1/2/4/8, row_bcast 15/31) -> lane 63
//   C. lane63 writes wave max to LDS[parity]; __syncthreads (barrier 1)
//   D. all threads: block max = max of 8 wave maxes (broadcast LDS reads)
//   E. threads with best==blockmax: downward scan for first matching p,
//      atomicMin(global flat index) -> exact jnp.argmax tie semantics
//   F. __syncthreads (barrier 2); read winner; broadcast centroid load (L2)
// Parity-indexed slots make the 2-barrier scheme race-free.
// ---------------------------------------------------------------------------
__global__ __launch_bounds__(FPS_THREADS, 1)
void fps_kernel(const float* __restrict__ xyz,       // [B, N, 3]
                const int* __restrict__ init_far,    // [B]
                int* __restrict__ idx_out,           // [B, S]
                float* __restrict__ newxyz_out)      // [B, S, 3]
{
    const int b = blockIdx.x;
    const int tid = threadIdx.x;
    const float* base = xyz + (size_t)b * NPTS * 3;

    __shared__ float s_pz[NPTS];                 // 64 KB
    __shared__ float s_wmax[2][NWAVE];
    __shared__ unsigned int s_idx[2];

    float px[PPT], py[PPT], dist[PPT];
#pragma unroll
    for (int p = 0; p < PPT; ++p) {
        const int i = tid + p * FPS_THREADS;     // ascending global index in p
        px[p] = base[i * 3 + 0];
        py[p] = base[i * 3 + 1];
        s_pz[i] = base[i * 3 + 2];
        dist[p] = 1e10f;
    }
    if (tid == 0) { s_idx[0] = 0xFFFFFFFFu; s_idx[1] = 0xFFFFFFFFu; }

    int cur = init_far[b];
    float cx = base[cur * 3 + 0];
    float cy = base[cur * 3 + 1];
    float cz = base[cur * 3 + 2];
    __syncthreads();

    const int lane = tid & 63;
    const int wave = tid >> 6;

    for (int s = 0; s < NSAMP; ++s) {
        const int q = s & 1;
        // record BEFORE update (reference scan semantics)
        if (tid == 0) {
            idx_out[b * NSAMP + s] = cur;
            float* o = newxyz_out + (size_t)(b * NSAMP + s) * 3;
            o[0] = cx; o[1] = cy; o[2] = cz;
        }

        // A: distance update + value-only per-thread max
        float best = 0.0f;
#pragma unroll
        for (int p = 0; p < PPT; p += 2) {
            const float z0 = s_pz[tid + p * FPS_THREADS];
            const float z1 = s_pz[tid + (p + 1) * FPS_THREADS];
            const float dx0 = __fsub_rn(px[p], cx);
            const float dy0 = __fsub_rn(py[p], cy);
            const float dz0 = __fsub_rn(z0, cz);
            const float d0  = __fadd_rn(__fadd_rn(__fmul_rn(dx0, dx0),
                                                  __fmul_rn(dy0, dy0)),
                                        __fmul_rn(dz0, dz0));
            const float dx1 = __fsub_rn(px[p + 1], cx);
            const float dy1 = __fsub_rn(py[p + 1], cy);
            const float dz1 = __fsub_rn(z1, cz);
            const float d1  = __fadd_rn(__fadd_rn(__fmul_rn(dx1, dx1),
                                                  __fmul_rn(dy1, dy1)),
                                        __fmul_rn(dz1, dz1));
            const float nd0 = fminf(dist[p], d0);
            const float nd1 = fminf(dist[p + 1], d1);
            dist[p] = nd0;
            dist[p + 1] = nd1;
            best = fmaxf(fmaxf(best, nd0), nd1);   // -> v_max3
        }

        // B: wave-level max via DPP (result complete in lane 63)
        float wv = best;
        wv = dpp_max<0x111>(wv);   // row_shr:1
        wv = dpp_max<0x112>(wv);   // row_shr:2
        wv = dpp_max<0x114>(wv);   // row_shr:4
        wv = dpp_max<0x118>(wv);   // row_shr:8
        wv = dpp_max<0x142>(wv);   // row_bcast:15
        wv = dpp_max<0x143>(wv);   // row_bcast:31
        if (lane == 63) s_wmax[q][wave] = wv;
        __syncthreads();           // barrier 1

        // D: block max (broadcast reads, all threads identical)
        float blkmax = s_wmax[q][0];
#pragma unroll
        for (int w = 1; w < NWAVE; ++w) blkmax = fmaxf(blkmax, s_wmax[q][w]);

        // reset the OTHER parity slot for iteration s+1 (safe window)
        if (tid == 0) s_idx[q ^ 1] = 0xFFFFFFFFu;

        // E: winner threads resolve lowest global index among exact matches
        if (best == blkmax) {
            int bp = 0;
#pragma unroll
            for (int p = PPT - 1; p >= 0; --p)
                if (dist[p] == blkmax) bp = p;       // downward -> smallest p
            atomicMin(&s_idx[q], (unsigned)(tid + bp * FPS_THREADS));
        }
        __syncthreads();           // barrier 2

        const int vi = (int)s_idx[q];
        cur = vi;
        // broadcast centroid load (uniform address, L2-resident)
        cx = base[vi * 3 + 0];
        cy = base[vi * 3 + 1];
        cz = base[vi * 3 + 2];
    }
}

// ---------------------------------------------------------------------------
// Kernel 2: gather selected rows, 1x1 conv (x @ W + b), ReLU.
// ---------------------------------------------------------------------------
#define SAMP_PER_BLK 16

__global__ __launch_bounds__(256)
void gather_linear_relu_kernel(const float* __restrict__ xyz,    // [B,N,3]
                               const float* __restrict__ feats,  // [B,N,F]
                               const int* __restrict__ idx,      // [B*S]
                               const float* __restrict__ W,      // [67,128]
                               const float* __restrict__ bias,   // [128]
                               float* __restrict__ out)          // [B*S,128]
{
    __shared__ float sW[C_IN][D_OUT];
    __shared__ float sX[SAMP_PER_BLK][C_IN + 1];
    __shared__ float sB[D_OUT];

    const int tid = threadIdx.x;

    for (int i = tid; i < C_IN * D_OUT; i += 256)
        (&sW[0][0])[i] = W[i];
    if (tid < D_OUT) sB[tid] = bias[tid];

    const int gs0 = blockIdx.x * SAMP_PER_BLK;

    {
        const int si = tid >> 4;
        const int j  = tid & 15;
        const int gs = gs0 + si;
        const int bb = gs >> 11;
        const int pt = idx[gs];
        const float* frow = feats + ((size_t)bb * NPTS + pt) * F_IN;
        const float* xrow = xyz   + ((size_t)bb * NPTS + pt) * 3;
        for (int c = j; c < F_IN; c += 16) sX[si][c] = frow[c];
        if (j < 3) sX[si][F_IN + j] = xrow[j];
    }
    __syncthreads();

    const int d = tid & 127;
    const int g = tid >> 7;
    float acc[8];
#pragma unroll
    for (int k = 0; k < 8; ++k) acc[k] = 0.0f;

    for (int c = 0; c < C_IN; ++c) {
        const float w = sW[c][d];
#pragma unroll
        for (int k = 0; k < 8; ++k)
            acc[k] = fmaf(sX[g * 8 + k][c], w, acc[k]);
    }

    const float bv = sB[d];
#pragma unroll
    for (int k = 0; k < 8; ++k) {
        const int gs = gs0 + g * 8 + k;
        const float v = acc[k] + bv;
        out[(size_t)gs * D_OUT + d] = fmaxf(v, 0.0f);
    }
}

// ---------------------------------------------------------------------------
extern "C" void kernel_launch(void* const* d_in, const int* in_sizes, int n_in,
                              void* d_out, int out_size, void* d_ws, size_t ws_size,
                              hipStream_t stream) {
    const float* xyz      = (const float*)d_in[0];
    const float* feats    = (const float*)d_in[1];
    const int*   init_far = (const int*)d_in[2];
    const float* W        = (const float*)d_in[3];
    const float* bias     = (const float*)d_in[4];

    float* out_newxyz = (float*)d_out;
    float* out_conv   = (float*)d_out + (size_t)B_SZ * NSAMP * 3;
    int*   idx_ws     = (int*)d_ws;

    fps_kernel<<<B_SZ, FPS_THREADS, 0, stream>>>(xyz, init_far, idx_ws, out_newxyz);

    const int nblocks = (B_SZ * NSAMP) / SAMP_PER_BLK;
    gather_linear_relu_kernel<<<nblocks, 256, 0, stream>>>(
        xyz, feats, idx_ws, W, bias, out_conv);
}